// Round 15
// baseline (431.069 us; speedup 1.0000x reference)
//
#include <hip/hip_runtime.h>
#include <stdint.h>

typedef unsigned int u32;
typedef unsigned long long u64;
typedef unsigned short u16;
typedef unsigned char u8;

#define NPTS 8192
#define CAP 20           // stored suppressor rows/point (lambda~3.1)
#define LROW 6           // rows preloaded+translated per point (P(>6)~3.7%)
#define INS 5            // LDS in-seg slots per rank (lambda~0.8, P(>5)~2e-4)
#define NSEG 4
#define SEGSZ 2048
#define NBRB (32 * 33)
#define RANKB 1024
#define TOTB (NBRB + RANKB)

// ---------------------------------------------------------------------------
// k_build: ONE kernel, two INDEPENDENT halves (verbatim from r14 -- passed).
//  blocks 0..1055: suppressor lists in ORIGINAL index space (triangular
//    tiles, direction by score-bit compare, tie -> smaller index wins;
//    edge stored on the suppressed side). d2<64 <=> sqrt(d2)<8 exactly.
//  blocks 1056..2079: exact stable rank of 8 points each; writes
//    sorted_id / rank_of / ss. Halves overlap across CUs.
// ---------------------------------------------------------------------------
__global__ __launch_bounds__(256) void k_build(const float* __restrict__ coords,
                                               const float* __restrict__ scores,
                                               u32* __restrict__ cnt,
                                               u16* __restrict__ nbr,
                                               u32* __restrict__ sorted_id,
                                               u32* __restrict__ rank_of,
                                               float* __restrict__ ss) {
  __shared__ u32 smem[NPTS];
  int b = blockIdx.x, t = threadIdx.x;

  if (b < NBRB) {
    float* qx = (float*)smem;
    float* qy = (float*)smem + 128;
    u32* qs = smem + 256;
    int R = (int)((__fsqrt_rn(4.0f * (float)b + 1.0f) - 1.0f) * 0.5f);
    while ((R + 1) * (R + 2) <= b) ++R;
    while (R * (R + 1) > b) --R;
    int C = b - R * (R + 1);
    int q0 = C << 7;
    int i = (R << 8) + t;
    if (t < 128) {
      int q = q0 + t;
      qx[t] = coords[2 * q];
      qy[t] = coords[2 * q + 1];
    } else {
      int u = t - 128;
      qs[u] = __float_as_uint(scores[q0 + u]);
    }
    __syncthreads();

    float x = coords[2 * i], y = coords[2 * i + 1];
    u32 si = __float_as_uint(scores[i]);
    int jlim = 128;
    int dC = C - 2 * R;
    if (dC >= 0) {
      jlim = t - (dC << 7);
      if (jlim < 0) jlim = 0;
      if (jlim > 128) jlim = 128;
    }
    const float4* x4 = (const float4*)qx;
    const float4* y4 = (const float4*)qy;
    for (int jg = 0; jg < 4; ++jg) {
      int base = jg << 5;
      int v = jlim - base;
      u32 gm = (v >= 32) ? 0xFFFFFFFFu : ((v <= 0) ? 0u : ((1u << v) - 1u));
      u32 m = 0;
#pragma unroll
      for (int j4 = 0; j4 < 8; ++j4) {
        float4 xv = x4[(base >> 2) + j4];
        float4 yv = y4[(base >> 2) + j4];
        // mirror reference arithmetic: sub, mul, mul, add (no fma)
        float dx0 = __fsub_rn(x, xv.x), dy0 = __fsub_rn(y, yv.x);
        float dx1 = __fsub_rn(x, xv.y), dy1 = __fsub_rn(y, yv.y);
        float dx2 = __fsub_rn(x, xv.z), dy2 = __fsub_rn(y, yv.z);
        float dx3 = __fsub_rn(x, xv.w), dy3 = __fsub_rn(y, yv.w);
        if (__fadd_rn(__fmul_rn(dx0, dx0), __fmul_rn(dy0, dy0)) < 64.0f) m |= 1u << (4 * j4 + 0);
        if (__fadd_rn(__fmul_rn(dx1, dx1), __fmul_rn(dy1, dy1)) < 64.0f) m |= 1u << (4 * j4 + 1);
        if (__fadd_rn(__fmul_rn(dx2, dx2), __fmul_rn(dy2, dy2)) < 64.0f) m |= 1u << (4 * j4 + 2);
        if (__fadd_rn(__fmul_rn(dx3, dx3), __fmul_rn(dy3, dy3)) < 64.0f) m |= 1u << (4 * j4 + 3);
      }
      m &= gm;
      while (m) {
        int j2 = __builtin_ctz(m);
        m &= m - 1;
        int q = q0 + base + j2;
        u32 sj = qs[base + j2];
        if (sj >= si) {       // q < i, so tie -> q higher priority
          u32 sl = atomicAdd(&cnt[i], 1u);
          if (sl < CAP) nbr[sl * NPTS + i] = (u16)q;
        } else {
          u32 sl = atomicAdd(&cnt[q], 1u);
          if (sl < CAP) nbr[sl * NPTS + q] = (u16)i;
        }
      }
    }
  } else {
    u32* skey = smem;
    int bi = b - NBRB;
    for (int k = t; k < NPTS; k += 256) skey[k] = __float_as_uint(scores[k]);
    __syncthreads();

    int g = t >> 5;
    int s = t & 31;
    int p = bi * 8 + g;
    u32 kp = skey[p];
    int sp = p >> 8;
    const uint4* k4 = (const uint4*)skey;
    int b4 = s << 6;
    u32 a = (s < sp) ? kp - 1u : kp;
    u32 c = 0, tc = 0;
    int qb = s << 8;
#pragma unroll 4
    for (int j = 0; j < 64; ++j) {
      int jj = (j + s) & 63;
      uint4 kv = k4[b4 + jj];
      int q = qb + (jj << 2);
      c += (kv.x > a) + (kv.y > a) + (kv.z > a) + (kv.w > a);
      tc += (kv.x == kp && q + 0 < p) + (kv.y == kp && q + 1 < p) +
            (kv.z == kp && q + 2 < p) + (kv.w == kp && q + 3 < p);
    }
    if (s < sp && kp == 0) c += 256;
    if (s == sp) c += tc;
    c += __shfl_xor(c, 1);
    c += __shfl_xor(c, 2);
    c += __shfl_xor(c, 4);
    c += __shfl_xor(c, 8);
    c += __shfl_xor(c, 16);
    if (s == 0) {
      sorted_id[c] = (u32)p;
      rank_of[p] = c;
      ss[c] = scores[p];  // bitwise copy keeps output exact
    }
  }
}

// ---------------------------------------------------------------------------
// k_nms: coalesced original-space loads + LDS redistribute + r13's verbatim
// round protocol. Thread t owns i = t + k*1024 (k<8): cnt + 6 rows loaded
// coalesced, translated to ranks once via an LDS rank table. Per segment:
// PUSH (owner-of-i resolves prefix suppression vs FINAL keep bits, scatters
// <=5 in-seg suppressor ranks into rank-indexed LDS slots; one writer per
// rank, no atomics) -> barrier -> owners-of-rank cache slots into REGISTERS
// -> triple-pass Gauss-Seidel rounds, rotating 4-slot flag, 1 barrier/round
// (r13's proven protocol; zero-flip round certifies the unique fixpoint =
// exact greedy). Rare: cnt>6 tail translated at push; in-seg>5 -> global
// rescan fallback (~2 points).
// ---------------------------------------------------------------------------
__global__ __launch_bounds__(1024) void k_nms(const u32* __restrict__ cnt,
                                              const u16* __restrict__ nbr,
                                              const u32* __restrict__ rank_of,
                                              const u32* __restrict__ sorted_id,
                                              const float* __restrict__ ss,
                                              float* __restrict__ out) {
  __shared__ u8 keep[NPTS];           // 8 KB
  __shared__ u16 rank16[NPTS];        // 16 KB
  __shared__ u16 insl[SEGSZ][INS];    // 20 KB
  __shared__ u16 iofs[SEGSZ];         // 4 KB
  __shared__ u8 inscnt[SEGSZ];        // 2 KB
  __shared__ int slot[4];
  int t = threadIdx.x;

  // ---- load phase: all coalesced / bulk-issued ----
  u32 c[8];
  u16 rq[8][LROW];
  u16 rk[8];
#pragma unroll
  for (int k = 0; k < 8; ++k) {
    int i = t + (k << 10);
    rank16[i] = (u16)rank_of[i];      // coalesced global -> LDS table
    u32 cc = cnt[i];
    c[k] = cc > CAP ? CAP : cc;
  }
#pragma unroll
  for (int k = 0; k < 8; ++k) {
    int i = t + (k << 10);
#pragma unroll
    for (int n = 0; n < LROW; ++n) rq[k][n] = nbr[n * NPTS + i];  // coalesced
  }
  __syncthreads();  // rank16 ready
#pragma unroll
  for (int k = 0; k < 8; ++k) {
    rk[k] = rank16[t + (k << 10)];
#pragma unroll
    for (int n = 0; n < LROW; ++n)
      rq[k][n] = rank16[rq[k][n] & (NPTS - 1)];  // mask: poison stays in-bounds
  }

  for (int s = 0; s < NSEG; ++s) {
    int S = s << 11;

    // ---- push phase: owner-of-i -> rank-indexed LDS ----
#pragma unroll
    for (int k = 0; k < 8; ++k) {
      if ((rk[k] >> 11) == s) {
        int i = t + (k << 10);
        int pl = rk[k] - S;
        bool presup = false;
        u32 ic = 0;
        u32 cc = c[k];
        u32 lim = cc < LROW ? cc : LROW;
        for (u32 n = 0; n < lim; ++n) {
          u32 q = rq[k][n];
          if ((int)q < S) presup |= (keep[q] != 0);  // prefix: FINAL
          else { if (ic < INS) insl[pl][ic] = (u16)q; ic++; }
        }
        for (u32 n = LROW; n < cc; ++n) {  // rare tail (~3.7% of points)
          u32 q = rank16[nbr[n * NPTS + i] & (NPTS - 1)];
          if ((int)q < S) presup |= (keep[q] != 0);
          else { if (ic < INS) insl[pl][ic] = (u16)q; ic++; }
        }
        keep[S + pl] = presup ? (u8)0 : (u8)1;
        u8 tag;
        if (presup) tag = 0xFF;
        else if (ic > INS) { tag = (u8)(0x80 | cc); iofs[pl] = (u16)i; }
        else tag = (u8)ic;
        inscnt[pl] = tag;
      }
    }
    if (t < 4) slot[t] = 0;
    __syncthreads();

    // ---- owners-of-rank: cache slots into registers (one LDS round-trip)
    u8 ic0 = inscnt[t], ic1 = inscnt[1024 + t];
    u16 s0[INS], s1[INS];
    u16 fi0 = 0, fi1 = 0;
    bool fb0 = (ic0 != 0xFF) && (ic0 & 0x80);
    bool fb1 = (ic1 != 0xFF) && (ic1 & 0x80);
    u32 n0 = fb0 ? 0 : (ic0 == 0xFF ? 0 : ic0);
    u32 n1 = fb1 ? 0 : (ic1 == 0xFF ? 0 : ic1);
#pragma unroll
    for (int n = 0; n < INS; ++n) {
      s0[n] = ((u32)n < n0) ? insl[t][n] : (u16)0xFFFF;
      s1[n] = ((u32)n < n1) ? insl[1024 + t][n] : (u16)0xFFFF;
    }
    if (fb0) fi0 = iofs[t];
    if (fb1) fi1 = iofs[1024 + t];
    u32 fc0 = fb0 ? (ic0 & 0x7F) : 0;
    u32 fc1 = fb1 ? (ic1 & 0x7F) : 0;
    bool act0 = (n0 > 0) || fb0;
    bool act1 = (n1 > 0) || fb1;
    int p0 = S + t, p1 = S + 1024 + t;

    // ---- eval rounds: triple-pass Gauss-Seidel, 1 barrier/round (r13) ----
    for (int r = 1; r <= SEGSZ + 2; ++r) {
      if (t == 0) slot[(r + 2) & 3] = 0;
      bool flip = false;
#pragma unroll
      for (int pass = 0; pass < 3; ++pass) {
        if (act0) {
          bool dead = false;
          if (s0[0] != 0xFFFF) dead |= (keep[s0[0]] != 0);
          if (s0[1] != 0xFFFF) dead |= (keep[s0[1]] != 0);
          if (s0[2] != 0xFFFF) dead |= (keep[s0[2]] != 0);
          if (s0[3] != 0xFFFF) dead |= (keep[s0[3]] != 0);
          if (s0[4] != 0xFFFF) dead |= (keep[s0[4]] != 0);
          if (fb0) {
            for (u32 n = 0; n < fc0; ++n) {
              u32 q = rank16[nbr[n * NPTS + fi0] & (NPTS - 1)];
              if ((int)q >= S) dead |= (keep[q] != 0);
            }
          }
          u8 a = dead ? (u8)0 : (u8)1;
          if (keep[p0] != a) { keep[p0] = a; flip = true; }
        }
        if (act1) {
          bool dead = false;
          if (s1[0] != 0xFFFF) dead |= (keep[s1[0]] != 0);
          if (s1[1] != 0xFFFF) dead |= (keep[s1[1]] != 0);
          if (s1[2] != 0xFFFF) dead |= (keep[s1[2]] != 0);
          if (s1[3] != 0xFFFF) dead |= (keep[s1[3]] != 0);
          if (s1[4] != 0xFFFF) dead |= (keep[s1[4]] != 0);
          if (fb1) {
            for (u32 n = 0; n < fc1; ++n) {
              u32 q = rank16[nbr[n * NPTS + fi1] & (NPTS - 1)];
              if ((int)q >= S) dead |= (keep[q] != 0);
            }
          }
          u8 a = dead ? (u8)0 : (u8)1;
          if (keep[p1] != a) { keep[p1] = a; flip = true; }
        }
      }
      if (flip) slot[r & 3] = 1;
      __syncthreads();
      if (slot[r & 3] == 0) break;  // full round w/o flips: exact fixpoint
    }
  }

  // epilogue: keep mask (original order) + suppressed scores (rank order)
  for (int k = t; k < NPTS; k += 1024) {
    u8 kp = keep[k];
    out[sorted_id[k]] = kp ? 1.0f : 0.0f;
    out[NPTS + k] = kp ? ss[k] : 0.0f;
  }
}

// ---------------------------------------------------------------------------
extern "C" void kernel_launch(void* const* d_in, const int* in_sizes, int n_in,
                              void* d_out, int out_size, void* d_ws, size_t ws_size,
                              hipStream_t stream) {
  const float* coords = (const float*)d_in[0];  // [N,2]
  const float* scores = (const float*)d_in[1];  // [N]
  float* out = (float*)d_out;                   // [N keep | N suppressed scores]

  char* ws = (char*)d_ws;
  size_t off = 0;
  u16* nbr       = (u16*)(ws + off); off += (size_t)CAP * NPTS * 2;  // 320K
  u32* sorted_id = (u32*)(ws + off); off += (size_t)NPTS * 4;        // 32K
  u32* rank_of   = (u32*)(ws + off); off += (size_t)NPTS * 4;        // 32K
  float* ss      = (float*)(ws + off); off += (size_t)NPTS * 4;      // 32K
  u32* cnt       = (u32*)(ws + off); off += (size_t)NPTS * 4;        // 32K

  hipMemsetAsync(cnt, 0, (size_t)NPTS * 4, stream);
  k_build<<<TOTB, 256, 0, stream>>>(coords, scores, cnt, nbr, sorted_id,
                                    rank_of, ss);
  k_nms<<<1, 1024, 0, stream>>>(cnt, nbr, rank_of, sorted_id, ss, out);
}

// Round 16
// 122.567 us; speedup vs baseline: 3.5170x; 3.5170x over previous
//
#include <hip/hip_runtime.h>
#include <stdint.h>

typedef unsigned int u32;
typedef unsigned long long u64;
typedef unsigned short u16;
typedef unsigned char u8;

#define NPTS 8192
#define CAPI 12          // in-segment rows stored (2048-seg lambda<=1.6)
#define CAPP 24          // prefix rows stored (lambda<=4.7)
#define NSEG 4
#define SEGSZ 2048
#define NTILES (32 * 33)
#define PRER 8           // unconditional prefix rows in round 0
#define INR 4            // unconditional in-seg rows (register-resident)

// ---------------------------------------------------------------------------
// A: rank by counting, register-tiled 4 points/thread (r10-r13 proven).
// Block 0 zeroes cnt_in | cnt_pre.
// ---------------------------------------------------------------------------
__global__ __launch_bounds__(1024) void k_rank(const float* __restrict__ coords,
                                               const float* __restrict__ scores,
                                               u32* __restrict__ sorted_id,
                                               float* __restrict__ sx,
                                               float* __restrict__ sy,
                                               float* __restrict__ ss,
                                               u32* __restrict__ zero_region) {
  __shared__ u32 skey[NPTS];
  __shared__ u32 part[16][4];
  int t = threadIdx.x, B = blockIdx.x;
  for (int k = t; k < NPTS; k += 1024) skey[k] = __float_as_uint(scores[k]);
  if (B == 0) {
    for (int k = t; k < 2 * NPTS; k += 1024) zero_region[k] = 0;
  }
  __syncthreads();

  int qd = t >> 7;        // quad 0..7 (4 points each)
  int s = t & 127;        // slice 0..127 (64 keys each)
  int p0 = B * 32 + qd * 4;
  int sp = B >> 1;        // the one slice containing this block's points
  u32 kp0 = skey[p0], kp1 = skey[p0 + 1], kp2 = skey[p0 + 2], kp3 = skey[p0 + 3];
  u32 c0 = 0, c1 = 0, c2 = 0, c3 = 0;
  const uint4* k4 = (const uint4*)skey;

  if (s != sp) {
    bool below = (s < sp);
    u32 a0 = below ? kp0 - 1u : kp0;  // >= via > (kp-1); kp==0 fixed below
    u32 a1 = below ? kp1 - 1u : kp1;
    u32 a2 = below ? kp2 - 1u : kp2;
    u32 a3 = below ? kp3 - 1u : kp3;
    int b4 = s << 4;
#pragma unroll 4
    for (int j = 0; j < 16; ++j) {
      int jj = (j + s) & 15;          // rotate across bank groups
      uint4 kv = k4[b4 + jj];
      c0 += (kv.x > a0) + (kv.y > a0) + (kv.z > a0) + (kv.w > a0);
      c1 += (kv.x > a1) + (kv.y > a1) + (kv.z > a1) + (kv.w > a1);
      c2 += (kv.x > a2) + (kv.y > a2) + (kv.z > a2) + (kv.w > a2);
      c3 += (kv.x > a3) + (kv.y > a3) + (kv.z > a3) + (kv.w > a3);
    }
    if (below) {  // underflow fixup: kp==0 means all 64 keys count as >=
      if (kp0 == 0) c0 += 64;
      if (kp1 == 0) c1 += 64;
      if (kp2 == 0) c2 += 64;
      if (kp3 == 0) c3 += 64;
    }
  } else {
    int q0 = s << 6;
    int mo = p0 - q0;  // 0..60, multiple of 4
    u32 a0 = kp0 - 1u, a1 = kp1 - 1u, a2 = kp2 - 1u, a3 = kp3 - 1u;
    for (int j = 0; j < mo; ++j) {       // q < p0: count >=
      u32 kq = skey[q0 + j];
      c0 += (kq > a0); c1 += (kq > a1); c2 += (kq > a2); c3 += (kq > a3);
    }
    if (kp0 == 0) c0 += mo;
    if (kp1 == 0) c1 += mo;
    if (kp2 == 0) c2 += mo;
    if (kp3 == 0) c3 += mo;
#pragma unroll
    for (int j2 = 0; j2 < 4; ++j2) {     // q in [p0, p0+4): exact tie logic
      int q = p0 + j2;
      u32 kq = skey[q];
      c0 += (kq > kp0) || (kq == kp0 && q < p0);
      c1 += (kq > kp1) || (kq == kp1 && q < p0 + 1);
      c2 += (kq > kp2) || (kq == kp2 && q < p0 + 2);
      c3 += (kq > kp3) || (kq == kp3 && q < p0 + 3);
    }
    for (int j = mo + 4; j < 64; ++j) {  // q > p_e: count >
      u32 kq = skey[q0 + j];
      c0 += (kq > kp0); c1 += (kq > kp1); c2 += (kq > kp2); c3 += (kq > kp3);
    }
  }

#pragma unroll
  for (int d = 1; d < 64; d <<= 1) {
    c0 += __shfl_xor(c0, d);
    c1 += __shfl_xor(c1, d);
    c2 += __shfl_xor(c2, d);
    c3 += __shfl_xor(c3, d);
  }
  int w = t >> 6;
  if ((t & 63) == 0) { part[w][0] = c0; part[w][1] = c1; part[w][2] = c2; part[w][3] = c3; }
  __syncthreads();
  if (t < 32) {
    int qd2 = t >> 2, e = t & 3;
    u32 r = part[qd2 * 2][e] + part[qd2 * 2 + 1][e];
    int p = B * 32 + t;
    sorted_id[r] = (u32)p;
    sx[r] = coords[2 * p];      // bitwise copies keep arithmetic exact
    sy[r] = coords[2 * p + 1];
    ss[r] = scores[p];
  }
}

// ---------------------------------------------------------------------------
// B: neighbor lists (triangular-tile lineage), split at build time into
// in-segment (same 2048-block) vs prefix lists. d2<64 <=> sqrt(d2)<8 exactly
// in f32 (correctly-rounded sqrt, 64 exact). Unchanged r10-r13.
// ---------------------------------------------------------------------------
__global__ __launch_bounds__(256) void k_nbr(const float* __restrict__ sx,
                                             const float* __restrict__ sy,
                                             u32* __restrict__ cnt_in,
                                             u32* __restrict__ cnt_pre,
                                             u16* __restrict__ nbr_in,
                                             u16* __restrict__ nbr_pre) {
  __shared__ float qx[128], qy[128];
  int b = blockIdx.x;
  int R = (int)((__fsqrt_rn(4.0f * (float)b + 1.0f) - 1.0f) * 0.5f);
  while ((R + 1) * (R + 2) <= b) ++R;
  while (R * (R + 1) > b) --R;
  int C = b - R * (R + 1);
  int t = threadIdx.x;
  int q0 = C << 7;
  int r = (R << 8) + t;
  if (t < 128) qx[t] = sx[q0 + t];
  else         qy[t - 128] = sy[q0 + t - 128];
  __syncthreads();

  float x = sx[r], y = sy[r];
  int jlim = 128;
  int dC = C - 2 * R;
  if (dC >= 0) {
    jlim = t - (dC << 7);
    if (jlim < 0) jlim = 0;
    if (jlim > 128) jlim = 128;
  }
  const float4* x4 = (const float4*)qx;
  const float4* y4 = (const float4*)qy;
  int rseg = r >> 11;
  for (int jg = 0; jg < 4; ++jg) {
    int base = jg << 5;
    int v = jlim - base;
    u32 gm = (v >= 32) ? 0xFFFFFFFFu : ((v <= 0) ? 0u : ((1u << v) - 1u));
    u32 m = 0;
#pragma unroll
    for (int j4 = 0; j4 < 8; ++j4) {
      float4 xv = x4[(base >> 2) + j4];
      float4 yv = y4[(base >> 2) + j4];
      // mirror reference arithmetic: sub, mul, mul, add (no fma contraction)
      float dx0 = __fsub_rn(x, xv.x), dy0 = __fsub_rn(y, yv.x);
      float dx1 = __fsub_rn(x, xv.y), dy1 = __fsub_rn(y, yv.y);
      float dx2 = __fsub_rn(x, xv.z), dy2 = __fsub_rn(y, yv.z);
      float dx3 = __fsub_rn(x, xv.w), dy3 = __fsub_rn(y, yv.w);
      if (__fadd_rn(__fmul_rn(dx0, dx0), __fmul_rn(dy0, dy0)) < 64.0f) m |= 1u << (4 * j4 + 0);
      if (__fadd_rn(__fmul_rn(dx1, dx1), __fmul_rn(dy1, dy1)) < 64.0f) m |= 1u << (4 * j4 + 1);
      if (__fadd_rn(__fmul_rn(dx2, dx2), __fmul_rn(dy2, dy2)) < 64.0f) m |= 1u << (4 * j4 + 2);
      if (__fadd_rn(__fmul_rn(dx3, dx3), __fmul_rn(dy3, dy3)) < 64.0f) m |= 1u << (4 * j4 + 3);
    }
    m &= gm;
    while (m) {  // rare: lambda ~3 hits/point total
      int j2 = __builtin_ctz(m);
      m &= m - 1;
      int q = q0 + base + j2;
      if ((q >> 11) == rseg) {
        u32 sl = atomicAdd(&cnt_in[r], 1u);
        if (sl < CAPI) nbr_in[sl * NPTS + r] = (u16)q;
      } else {
        u32 sl = atomicAdd(&cnt_pre[r], 1u);
        if (sl < CAPP) nbr_pre[sl * NPTS + r] = (u16)q;
      }
    }
  }
}

// ---------------------------------------------------------------------------
// C: r13's proven fixpoint, byte-for-byte (1024 thr, 2 pts/thread, 4x2048
// segments, register rows, TRIPLE-pass Gauss-Seidel, rotating 4-slot flag,
// 1 barrier/round). 42.7us measured; r14 (scattered rows) and r15 (spilled
// redistribute) both regressed badly -- this is the measured local optimum.
// ---------------------------------------------------------------------------
__global__ __launch_bounds__(1024) void k_nms(const u32* __restrict__ cnt_in,
                                              const u32* __restrict__ cnt_pre,
                                              const u16* __restrict__ nbr_in,
                                              const u16* __restrict__ nbr_pre,
                                              const u32* __restrict__ sorted_id,
                                              const float* __restrict__ ss,
                                              float* __restrict__ out) {
  __shared__ u8 keep[NPTS];
  __shared__ int slot[4];
  int t = threadIdx.x;

  // prefetch segment 0
  u32 ciA_n = cnt_in[t], ciB_n = cnt_in[1024 + t];
  u32 cpA_n = cnt_pre[t], cpB_n = cnt_pre[1024 + t];
  u16 preA_n[PRER], preB_n[PRER], inA_n[INR], inB_n[INR];
#pragma unroll
  for (int n = 0; n < PRER; ++n) {
    preA_n[n] = nbr_pre[n * NPTS + t];
    preB_n[n] = nbr_pre[n * NPTS + 1024 + t];
  }
#pragma unroll
  for (int n = 0; n < INR; ++n) {
    inA_n[n] = nbr_in[n * NPTS + t];
    inB_n[n] = nbr_in[n * NPTS + 1024 + t];
  }

  for (int s = 0; s < NSEG; ++s) {
    int segbase = s << 11;
    int pA = segbase + t, pB = segbase + 1024 + t;
    u32 ciA = ciA_n, ciB = ciB_n, cpA = cpA_n, cpB = cpB_n;
    if (ciA > CAPI) ciA = CAPI;
    if (ciB > CAPI) ciB = CAPI;
    if (cpA > CAPP) cpA = CAPP;
    if (cpB > CAPP) cpB = CAPP;
    u16 preA[PRER], preB[PRER], inA[INR], inB[INR];
#pragma unroll
    for (int n = 0; n < PRER; ++n) { preA[n] = preA_n[n]; preB[n] = preB_n[n]; }
#pragma unroll
    for (int n = 0; n < INR; ++n) { inA[n] = inA_n[n]; inB[n] = inB_n[n]; }

    if (s < 3) {  // issue next segment's loads now (hidden behind rounds)
      int b = segbase + SEGSZ;
      ciA_n = cnt_in[b + t];
      ciB_n = cnt_in[b + 1024 + t];
      cpA_n = cnt_pre[b + t];
      cpB_n = cnt_pre[b + 1024 + t];
#pragma unroll
      for (int n = 0; n < PRER; ++n) {
        preA_n[n] = nbr_pre[n * NPTS + b + t];
        preB_n[n] = nbr_pre[n * NPTS + b + 1024 + t];
      }
#pragma unroll
      for (int n = 0; n < INR; ++n) {
        inA_n[n] = nbr_in[n * NPTS + b + t];
        inB_n[n] = nbr_in[n * NPTS + b + 1024 + t];
      }
    }

    // ---- round 0: prefix suppression vs FINAL bits; in-seg rows -> regs
    bool supA = false, supB = false;
#pragma unroll
    for (int n = 0; n < PRER; ++n) {
      if ((u32)n < cpA) supA |= (keep[preA[n]] != 0);
      if ((u32)n < cpB) supB |= (keep[preB[n]] != 0);
    }
    for (u32 n = PRER; n < cpA; ++n)  // tail: ~5% of points, round-0 only
      supA |= (keep[nbr_pre[n * NPTS + pA]] != 0);
    for (u32 n = PRER; n < cpB; ++n)
      supB |= (keep[nbr_pre[n * NPTS + pB]] != 0);
    keep[pA] = supA ? (u8)0 : (u8)1;
    keep[pB] = supB ? (u8)0 : (u8)1;
    u32 kinA = ciA < INR ? ciA : INR;
    u32 kinB = ciB < INR ? ciB : INR;
#pragma unroll
    for (int n = 0; n < INR; ++n) {
      if ((u32)n >= kinA) inA[n] = 0xFFFF;
      if ((u32)n >= kinB) inB[n] = 0xFFFF;
    }
    u32 tailA = (ciA > INR) ? ciA : 0;  // rare: rescan global rows 4..ci
    u32 tailB = (ciB > INR) ? ciB : 0;
    bool actA = !supA && (ciA > 0);
    bool actB = !supB && (ciB > 0);
    if (t < 4) slot[t] = 0;
    __syncthreads();

    // ---- eval rounds: TRIPLE-pass Gauss-Seidel, 1 barrier/round ----
    for (int r = 1; r <= SEGSZ + 2; ++r) {
      if (t == 0) slot[(r + 2) & 3] = 0;
      bool flip = false;
#pragma unroll
      for (int pass = 0; pass < 3; ++pass) {
        if (actA) {
          bool dead = false;
          if (inA[0] != 0xFFFF) dead |= (keep[inA[0]] != 0);
          if (inA[1] != 0xFFFF) dead |= (keep[inA[1]] != 0);
          if (inA[2] != 0xFFFF) dead |= (keep[inA[2]] != 0);
          if (inA[3] != 0xFFFF) dead |= (keep[inA[3]] != 0);
          if (tailA)
            for (u32 n = INR; n < tailA; ++n)
              dead |= (keep[nbr_in[n * NPTS + pA]] != 0);
          u8 a = dead ? (u8)0 : (u8)1;
          if (keep[pA] != a) { keep[pA] = a; flip = true; }
        }
        if (actB) {
          bool dead = false;
          if (inB[0] != 0xFFFF) dead |= (keep[inB[0]] != 0);
          if (inB[1] != 0xFFFF) dead |= (keep[inB[1]] != 0);
          if (inB[2] != 0xFFFF) dead |= (keep[inB[2]] != 0);
          if (inB[3] != 0xFFFF) dead |= (keep[inB[3]] != 0);
          if (tailB)
            for (u32 n = INR; n < tailB; ++n)
              dead |= (keep[nbr_in[n * NPTS + pB]] != 0);
          u8 a = dead ? (u8)0 : (u8)1;
          if (keep[pB] != a) { keep[pB] = a; flip = true; }
        }
      }
      if (flip) slot[r & 3] = 1;
      __syncthreads();
      if (slot[r & 3] == 0) break;  // full round w/o flips: exact fixpoint
    }
  }

  // epilogue: keep mask (original order) + suppressed scores (rank order)
  for (int k = t; k < NPTS; k += 1024) {
    u8 kp = keep[k];
    out[sorted_id[k]] = kp ? 1.0f : 0.0f;
    out[NPTS + k] = kp ? ss[k] : 0.0f;
  }
}

// ---------------------------------------------------------------------------
extern "C" void kernel_launch(void* const* d_in, const int* in_sizes, int n_in,
                              void* d_out, int out_size, void* d_ws, size_t ws_size,
                              hipStream_t stream) {
  const float* coords = (const float*)d_in[0];  // [N,2]
  const float* scores = (const float*)d_in[1];  // [N]
  float* out = (float*)d_out;                   // [N keep | N suppressed scores]

  char* ws = (char*)d_ws;
  size_t off = 0;
  u16* nbr_in    = (u16*)(ws + off); off += (size_t)CAPI * NPTS * 2;  // 192K
  u16* nbr_pre   = (u16*)(ws + off); off += (size_t)CAPP * NPTS * 2;  // 384K
  u32* sorted_id = (u32*)(ws + off); off += (size_t)NPTS * 4;         // 32K
  float* sx      = (float*)(ws + off); off += (size_t)NPTS * 4;       // 32K
  float* sy      = (float*)(ws + off); off += (size_t)NPTS * 4;       // 32K
  float* ss      = (float*)(ws + off); off += (size_t)NPTS * 4;       // 32K
  u32* zero      = (u32*)(ws + off); off += (size_t)(2 * NPTS) * 4;
  u32* cnt_in  = zero;
  u32* cnt_pre = zero + NPTS;

  k_rank<<<256, 1024, 0, stream>>>(coords, scores, sorted_id, sx, sy, ss, zero);
  k_nbr<<<NTILES, 256, 0, stream>>>(sx, sy, cnt_in, cnt_pre, nbr_in, nbr_pre);
  k_nms<<<1, 1024, 0, stream>>>(cnt_in, cnt_pre, nbr_in, nbr_pre, sorted_id,
                                ss, out);
}